// Round 8
// baseline (185.078 us; speedup 1.0000x reference)
//
#include <hip/hip_runtime.h>
#include <hip/hip_bf16.h>
#include <stdint.h>

#define IN_CH 256
#define HC    128   // HEADS * C
#define HEADS 4
#define CPH   32    // channels per head
#define NEG_SLOPE 0.2f

using f32x4  = __attribute__((ext_vector_type(4))) float;
using bf16x8 = __attribute__((ext_vector_type(8))) short;

// ---------- K_prep: W [256][128] f32 -> W^T hi/lo bf16 [128 cols][256 k] ----------
__global__ __launch_bounds__(256) void k_prep(const float* __restrict__ W,
                                              unsigned short* __restrict__ wthi,
                                              unsigned short* __restrict__ wtlo) {
    __shared__ unsigned short shh[128][18];
    __shared__ unsigned short shl[128][18];
    const int t = threadIdx.x, b = blockIdx.x;
    const int k0 = b * 16;
#pragma unroll
    for (int j = 0; j < 8; ++j) {
        int idx = t + j * 256;
        int kk = idx >> 7, c = idx & 127;
        float v = W[(size_t)(k0 + kk) * HC + c];
        unsigned int u = __float_as_uint(v);
        float fl = v - __uint_as_float(u & 0xFFFF0000u);
        shh[c][kk] = (unsigned short)(u >> 16);
        shl[c][kk] = (unsigned short)(__float_as_uint(fl) >> 16);
    }
    __syncthreads();
    const int c = t & 127, seg = t >> 7;
    unsigned short tmp[8];
    uint4 o;
#pragma unroll
    for (int i = 0; i < 8; ++i) tmp[i] = shh[c][seg * 8 + i];
    o.x = tmp[0] | ((unsigned int)tmp[1] << 16);
    o.y = tmp[2] | ((unsigned int)tmp[3] << 16);
    o.z = tmp[4] | ((unsigned int)tmp[5] << 16);
    o.w = tmp[6] | ((unsigned int)tmp[7] << 16);
    *(uint4*)(wthi + (size_t)c * IN_CH + k0 + seg * 8) = o;
#pragma unroll
    for (int i = 0; i < 8; ++i) tmp[i] = shl[c][seg * 8 + i];
    o.x = tmp[0] | ((unsigned int)tmp[1] << 16);
    o.y = tmp[2] | ((unsigned int)tmp[3] << 16);
    o.z = tmp[4] | ((unsigned int)tmp[5] << 16);
    o.w = tmp[6] | ((unsigned int)tmp[7] << 16);
    *(uint4*)(wtlo + (size_t)c * IN_CH + k0 + seg * 8) = o;
}

// f32x8 -> bf16 hi/lo frags (truncation split)
__device__ inline void cvt_hilo(const float4& a, const float4& b, bf16x8& hi, bf16x8& lo) {
    const float f[8] = {a.x, a.y, a.z, a.w, b.x, b.y, b.z, b.w};
#pragma unroll
    for (int e = 0; e < 8; ++e) {
        unsigned int u = __float_as_uint(f[e]);
        hi[e] = (short)(u >> 16);
        float fl = f[e] - __uint_as_float(u & 0xFFFF0000u);
        lo[e] = (short)(__float_as_uint(fl) >> 16);
    }
}

// ---------- K_gemm v8: MFMA bf16x2 split GEMM, software-pipelined ----------
// One wave per 16 rows x 128 cols -> 2500 waves (2.4/SIMD offered). Fully-unrolled
// kc loop (8 steps), half-kc register pipeline with FIXED-ROLE buffers (static
// indices): phase0 {issue G1(kc) loads; MFMA G0(kc)}, phase1 {issue G0(kc+32)+A
// prefetch; MFMA G1(kc)}. Every load has a compute phase + 3 resident waves to
// hide its L2/HBM latency. No LDS, no barriers.
__global__ __launch_bounds__(256) void k_gemm(const float* __restrict__ x,
                                              const unsigned short* __restrict__ wthi,
                                              const unsigned short* __restrict__ wtlo,
                                              const float* __restrict__ att_src,
                                              const float* __restrict__ att_dst,
                                              float* __restrict__ xp,
                                              float* __restrict__ asrc,
                                              float* __restrict__ adst,
                                              int* __restrict__ cnt, int n) {
    const int wave = blockIdx.x * 4 + (threadIdx.x >> 6);
    const int m0 = wave * 16;
    if (m0 >= n) return;
    const int l  = threadIdx.x & 63;
    const int lr = l & 15;
    const int q  = l >> 4;
    const int kq = q * 8;   // lane k-offset within a 32-k step

    f32x4 acc[8];
    const f32x4 zero = {0.f, 0.f, 0.f, 0.f};
#pragma unroll
    for (int j = 0; j < 8; ++j) acc[j] = zero;

    const int arow_idx = (m0 + lr < n) ? (m0 + lr) : (n - 1);
    const float* arow = x + (size_t)arow_idx * IN_CH + kq;
    const unsigned short* bh = wthi + (size_t)lr * IN_CH + kq;
    const unsigned short* bl = wtlo + (size_t)lr * IN_CH + kq;

    // A double buffer (ping-pong by s&1, static after full unroll)
    float4 aLb[2], aHb[2];
    aLb[0] = *(const float4*)(arow);
    aHb[0] = *(const float4*)(arow + 4);

    // B stage: fixed roles. sb*[0][j] = ct j (G0), sb*[1][j] = ct j+4 (G1).
    uint4 sbh[2][4], sbl[2][4];
#pragma unroll
    for (int j = 0; j < 4; ++j) {
        sbh[0][j] = *(const uint4*)(bh + (size_t)j * 16 * IN_CH);
        sbl[0][j] = *(const uint4*)(bl + (size_t)j * 16 * IN_CH);
    }

#pragma unroll
    for (int s = 0; s < 8; ++s) {
        const int kc = s * 32;
        const int p = s & 1, pn = p ^ 1;
        bf16x8 ahi, alo;
        cvt_hilo(aLb[p], aHb[p], ahi, alo);
        // ---- phase 0: issue G1(kc) loads; MFMA G0(kc) ----
#pragma unroll
        for (int j = 0; j < 4; ++j) {
            sbh[1][j] = *(const uint4*)(bh + (size_t)(j + 4) * 16 * IN_CH + kc);
            sbl[1][j] = *(const uint4*)(bl + (size_t)(j + 4) * 16 * IN_CH + kc);
        }
#pragma unroll
        for (int j = 0; j < 4; ++j) {
            bf16x8 bhi = __builtin_bit_cast(bf16x8, sbh[0][j]);
            bf16x8 blo = __builtin_bit_cast(bf16x8, sbl[0][j]);
            acc[j] = __builtin_amdgcn_mfma_f32_16x16x32_bf16(alo, bhi, acc[j], 0, 0, 0);
            acc[j] = __builtin_amdgcn_mfma_f32_16x16x32_bf16(ahi, blo, acc[j], 0, 0, 0);
            acc[j] = __builtin_amdgcn_mfma_f32_16x16x32_bf16(ahi, bhi, acc[j], 0, 0, 0);
        }
        // ---- phase 1: issue G0(kc+32) + A prefetch; MFMA G1(kc) ----
        if (s < 7) {
#pragma unroll
            for (int j = 0; j < 4; ++j) {
                sbh[0][j] = *(const uint4*)(bh + (size_t)j * 16 * IN_CH + kc + 32);
                sbl[0][j] = *(const uint4*)(bl + (size_t)j * 16 * IN_CH + kc + 32);
            }
            aLb[pn] = *(const float4*)(arow + kc + 32);
            aHb[pn] = *(const float4*)(arow + kc + 36);
        }
#pragma unroll
        for (int j = 0; j < 4; ++j) {
            bf16x8 bhi = __builtin_bit_cast(bf16x8, sbh[1][j]);
            bf16x8 blo = __builtin_bit_cast(bf16x8, sbl[1][j]);
            acc[4 + j] = __builtin_amdgcn_mfma_f32_16x16x32_bf16(alo, bhi, acc[4 + j], 0, 0, 0);
            acc[4 + j] = __builtin_amdgcn_mfma_f32_16x16x32_bf16(ahi, blo, acc[4 + j], 0, 0, 0);
            acc[4 + j] = __builtin_amdgcn_mfma_f32_16x16x32_bf16(ahi, bhi, acc[4 + j], 0, 0, 0);
        }
    }

    // ---- fused attention dots: per row, per head, reduce over the 16 col-lanes ----
    float as_c[8], ad_c[8];
#pragma unroll
    for (int ct = 0; ct < 8; ++ct) {
        as_c[ct] = att_src[ct * 16 + lr];
        ad_c[ct] = att_dst[ct * 16 + lr];
    }
#pragma unroll
    for (int h = 0; h < 4; ++h)
#pragma unroll
        for (int r = 0; r < 4; ++r) {
            float s = acc[2 * h][r] * as_c[2 * h] + acc[2 * h + 1][r] * as_c[2 * h + 1];
            float d = acc[2 * h][r] * ad_c[2 * h] + acc[2 * h + 1][r] * ad_c[2 * h + 1];
            s += __shfl_xor(s, 1, 64); s += __shfl_xor(s, 2, 64);
            s += __shfl_xor(s, 4, 64); s += __shfl_xor(s, 8, 64);
            d += __shfl_xor(d, 1, 64); d += __shfl_xor(d, 2, 64);
            d += __shfl_xor(d, 4, 64); d += __shfl_xor(d, 8, 64);
            if (lr == h) {
                int row = m0 + q * 4 + r;
                if (row < n) {
                    asrc[(size_t)row * 4 + h] = s;
                    adst[(size_t)row * 4 + h] = d;
                }
            }
        }

    // ---- xp store (verified C/D layout) + cnt=1 self-loop ----
#pragma unroll
    for (int r = 0; r < 4; ++r) {
        int row = m0 + q * 4 + r;
        if (row < n) {
            if (lr == 8) cnt[row] = 1;
            float* xr = xp + (size_t)row * HC + lr;
#pragma unroll
            for (int ct = 0; ct < 8; ++ct)
                xr[ct * 16] = acc[ct][r];
        }
    }
}

// ---------- K_count ----------
__global__ void k_count(const int* __restrict__ ei, int* __restrict__ cnt, int E) {
    int e = blockIdx.x * blockDim.x + threadIdx.x;
    if (e >= E) return;
    atomicAdd(cnt + ei[E + e], 1);
}

// ---------- hierarchical scan: chunk=1024 ----------
__global__ __launch_bounds__(256) void k_scan1(const int* __restrict__ cnt,
                                               int* __restrict__ bsum, int n) {
    __shared__ int sm[256];
    int b = blockIdx.x, t = threadIdx.x;
    int base = b << 10;
    int s = 0;
#pragma unroll
    for (int j = 0; j < 4; ++j) {
        int i = base + t + j * 256;
        if (i < n) s += cnt[i];
    }
    sm[t] = s;
    __syncthreads();
    for (int d = 128; d > 0; d >>= 1) {
        if (t < d) sm[t] += sm[t + d];
        __syncthreads();
    }
    if (t == 0) bsum[b] = sm[0];
}

__global__ __launch_bounds__(1024) void k_scan2(int* __restrict__ bsum,
                                                int* __restrict__ offs,
                                                int nb, int n, int total) {
    __shared__ int sm[1024];
    int t = threadIdx.x;
    int orig = (t < nb) ? bsum[t] : 0;
    sm[t] = orig;
    __syncthreads();
    for (int d = 1; d < 1024; d <<= 1) {
        int v = (t >= d) ? sm[t - d] : 0;
        __syncthreads();
        sm[t] += v;
        __syncthreads();
    }
    if (t < nb) bsum[t] = sm[t] - orig;
    if (t == 0) offs[n] = total;
}

__global__ __launch_bounds__(256) void k_scan3(const int* __restrict__ cnt,
                                               const int* __restrict__ bsum,
                                               int* __restrict__ offs,
                                               int* __restrict__ cursor, int n) {
    __shared__ int sm[256];
    int b = blockIdx.x, t = threadIdx.x;
    int base = (b << 10) + t * 4;
    int c[4];
    int s = 0;
#pragma unroll
    for (int j = 0; j < 4; ++j) {
        int i = base + j;
        c[j] = (i < n) ? cnt[i] : 0;
        s += c[j];
    }
    sm[t] = s;
    __syncthreads();
    for (int d = 1; d < 256; d <<= 1) {
        int v = (t >= d) ? sm[t - d] : 0;
        __syncthreads();
        sm[t] += v;
        __syncthreads();
    }
    int excl = bsum[b] + ((t == 0) ? 0 : sm[t - 1]);
#pragma unroll
    for (int j = 0; j < 4; ++j) {
        int i = base + j;
        if (i < n) { offs[i] = excl; cursor[i] = excl; }
        excl += c[j];
    }
}

// ---------- K_fill ----------
__global__ void k_fill(const int* __restrict__ ei, int* __restrict__ cursor,
                       int* __restrict__ srcs, int E, int n) {
    int e = blockIdx.x * blockDim.x + threadIdx.x;
    if (e >= E + n) return;
    int s, d;
    if (e < E) { s = ei[e]; d = ei[E + e]; } else { s = d = e - E; }
    int pos = atomicAdd(cursor + d, 1);
    srcs[pos] = s;
}

// ---------- K_gat: one wave per dst node (unchanged) ----------
__global__ __launch_bounds__(256) void k_gat(const int* __restrict__ offs,
                                             const int* __restrict__ srcs,
                                             const float* __restrict__ asrc,
                                             const float* __restrict__ adst,
                                             const float* __restrict__ xp,
                                             const float* __restrict__ bias,
                                             float* __restrict__ out, int n) {
    __shared__ int sS[4][128];
    const int wid = threadIdx.x >> 6;
    const int wave = blockIdx.x * 4 + wid;
    if (wave >= n) return;
    const int lane = threadIdx.x & 63;
    const int d = wave;
    const int start = offs[d], end = offs[d + 1];
    const int deg = end - start;

    const int h = lane & 3;
    const float ad_h = adst[(size_t)d * 4 + h];
    float m = -1e30f, Z = 0.f;

    for (int c0 = start; c0 < end; c0 += 128) {
        const int cn = min(128, end - c0);
        if (c0 + lane < end)      sS[wid][lane]      = srcs[c0 + lane];
        if (c0 + 64 + lane < end) sS[wid][64 + lane] = srcs[c0 + 64 + lane];
        asm volatile("s_waitcnt lgkmcnt(0)" ::: "memory");
        for (int i = (lane >> 2); i < cn; i += 16) {
            int s = sS[wid][i];
            float t = asrc[(size_t)s * 4 + h] + ad_h;
            t = t > 0.f ? t : NEG_SLOPE * t;
            float nm = fmaxf(m, t);
            Z = Z * __expf(m - nm) + __expf(t - nm);
            m = nm;
        }
    }
#pragma unroll
    for (int off = 4; off < 64; off <<= 1) {
        float om = __shfl_xor(m, off, 64);
        float oZ = __shfl_xor(Z, off, 64);
        float nm = fmaxf(m, om);
        Z = Z * __expf(m - nm) + oZ * __expf(om - nm);
        m = nm;
    }

    const int cl = lane & 15;
    const int eg = lane >> 4;
    const int hh = cl >> 2;
    const float m2  = __shfl(m, hh, 64);
    const float rZ  = 1.0f / __shfl(Z, hh, 64);
    const float ad2 = __shfl(ad_h, hh, 64);

    float4 a0 = make_float4(0.f, 0.f, 0.f, 0.f);
    float4 a1 = make_float4(0.f, 0.f, 0.f, 0.f);

    for (int c0 = start; c0 < end; c0 += 128) {
        const int cn = min(128, end - c0);
        if (deg > 128) {
            if (c0 + lane < end)      sS[wid][lane]      = srcs[c0 + lane];
            if (c0 + 64 + lane < end) sS[wid][64 + lane] = srcs[c0 + 64 + lane];
            asm volatile("s_waitcnt lgkmcnt(0)" ::: "memory");
        }
        const int full = cn & ~7;
        int i = 0;
        for (; i < full; i += 8) {
            int sa = sS[wid][i + eg];
            int sb = sS[wid][i + 4 + eg];
            float ta = asrc[(size_t)sa * 4 + hh] + ad2;
            float tb = asrc[(size_t)sb * 4 + hh] + ad2;
            const float4* xa = (const float4*)(xp + (size_t)sa * HC + cl * 8);
            const float4* xb = (const float4*)(xp + (size_t)sb * HC + cl * 8);
            float4 va0 = xa[0], va1 = xa[1];
            float4 vb0 = xb[0], vb1 = xb[1];
            ta = ta > 0.f ? ta : NEG_SLOPE * ta;
            tb = tb > 0.f ? tb : NEG_SLOPE * tb;
            float aa = __expf(ta - m2) * rZ;
            float ab = __expf(tb - m2) * rZ;
            a0.x += aa * va0.x; a0.y += aa * va0.y; a0.z += aa * va0.z; a0.w += aa * va0.w;
            a1.x += aa * va1.x; a1.y += aa * va1.y; a1.z += aa * va1.z; a1.w += aa * va1.w;
            a0.x += ab * vb0.x; a0.y += ab * vb0.y; a0.z += ab * vb0.z; a0.w += ab * vb0.w;
            a1.x += ab * vb1.x; a1.y += ab * vb1.y; a1.z += ab * vb1.z; a1.w += ab * vb1.w;
        }
        for (; i < cn; i += 4) {
            if (i + eg < cn) {
                int s = sS[wid][i + eg];
                float t = asrc[(size_t)s * 4 + hh] + ad2;
                const float4* xr = (const float4*)(xp + (size_t)s * HC + cl * 8);
                float4 v0 = xr[0], v1 = xr[1];
                t = t > 0.f ? t : NEG_SLOPE * t;
                float al = __expf(t - m2) * rZ;
                a0.x += al * v0.x; a0.y += al * v0.y; a0.z += al * v0.z; a0.w += al * v0.w;
                a1.x += al * v1.x; a1.y += al * v1.y; a1.z += al * v1.z; a1.w += al * v1.w;
            }
        }
    }

#pragma unroll
    for (int off = 16; off < 64; off <<= 1) {
        a0.x += __shfl_xor(a0.x, off, 64); a0.y += __shfl_xor(a0.y, off, 64);
        a0.z += __shfl_xor(a0.z, off, 64); a0.w += __shfl_xor(a0.w, off, 64);
        a1.x += __shfl_xor(a1.x, off, 64); a1.y += __shfl_xor(a1.y, off, 64);
        a1.z += __shfl_xor(a1.z, off, 64); a1.w += __shfl_xor(a1.w, off, 64);
    }

    if (eg == 0) {
        const float4* bp = (const float4*)bias + cl * 2;
        float4 b0 = bp[0], b1 = bp[1];
        float4 o0, o1;
        o0.x = fmaxf(a0.x + b0.x, 0.f); o0.y = fmaxf(a0.y + b0.y, 0.f);
        o0.z = fmaxf(a0.z + b0.z, 0.f); o0.w = fmaxf(a0.w + b0.w, 0.f);
        o1.x = fmaxf(a1.x + b1.x, 0.f); o1.y = fmaxf(a1.y + b1.y, 0.f);
        o1.z = fmaxf(a1.z + b1.z, 0.f); o1.w = fmaxf(a1.w + b1.w, 0.f);
        float4* op = (float4*)(out + (size_t)d * HC) + cl * 2;
        op[0] = o0; op[1] = o1;
    }
}

extern "C" void kernel_launch(void* const* d_in, const int* in_sizes, int n_in,
                              void* d_out, int out_size, void* d_ws, size_t ws_size,
                              hipStream_t stream) {
    const float* x       = (const float*)d_in[0];
    const int*   ei      = (const int*)d_in[1];
    const float* W       = (const float*)d_in[3];
    const float* att_src = (const float*)d_in[4];
    const float* att_dst = (const float*)d_in[5];
    const float* bias    = (const float*)d_in[6];
    float* out = (float*)d_out;

    const int n = in_sizes[0] / IN_CH;   // 40000
    const int E = in_sizes[1] / 2;       // 640000
    const int EN = E + n;
    const int NB = (n + 1023) >> 10;     // scan chunks

    // workspace layout
    float* xp   = (float*)d_ws;                          // n*128 f32
    float* asrc = xp + (size_t)n * HC;                   // n*4
    float* adst = asrc + (size_t)n * HEADS;              // n*4
    int*   cnt    = (int*)(adst + (size_t)n * HEADS);    // n
    int*   offs   = cnt + n;                             // n+1
    int*   cursor = offs + n + 1;                        // n
    int*   bsum   = cursor + n;                          // NB
    int*   srcs   = bsum + 1024;                         // E+n
    unsigned short* wthi = (unsigned short*)(((uintptr_t)(srcs + EN) + 63) & ~(uintptr_t)63);
    unsigned short* wtlo = wthi + (size_t)HC * IN_CH;    // 64 KB each

    k_prep<<<16, 256, 0, stream>>>(W, wthi, wtlo);
    {
        const int nwaves = (n + 15) / 16;
        k_gemm<<<(nwaves + 3) / 4, 256, 0, stream>>>(x, wthi, wtlo, att_src, att_dst,
                                                     xp, asrc, adst, cnt, n);
    }
    k_count<<<(E + 255) / 256, 256, 0, stream>>>(ei, cnt, E);
    k_scan1<<<NB, 256, 0, stream>>>(cnt, bsum, n);
    k_scan2<<<1, 1024, 0, stream>>>(bsum, offs, NB, n, EN);
    k_scan3<<<NB, 256, 0, stream>>>(cnt, bsum, offs, cursor, n);
    k_fill<<<(EN + 255) / 256, 256, 0, stream>>>(ei, cursor, srcs, E, n);
    k_gat<<<(n + 3) / 4, 256, 0, stream>>>(offs, srcs, asrc, adst, xp, bias, out, n);
}

// Round 9
// 158.470 us; speedup vs baseline: 1.1679x; 1.1679x over previous
//
#include <hip/hip_runtime.h>
#include <hip/hip_bf16.h>
#include <stdint.h>

#define IN_CH 256
#define HC    128   // HEADS * C
#define HEADS 4
#define CPH   32    // channels per head
#define NEG_SLOPE 0.2f

using f32x4  = __attribute__((ext_vector_type(4))) float;
using bf16x8 = __attribute__((ext_vector_type(8))) short;

// ---------- K_prep v2: W [256][128] f32 -> wpk, lane-order packed bf16 hi/lo ----------
// wpk layout: uint4 index ((s*8 + ct)*2 + hilo)*64 + lane, s=k-step(32), ct=col-tile(16).
// Lane l's fragment: col = ct*16 + (l&15), k = s*32 + (l>>4)*8 + e  (e=0..7).
// So each (s,ct,hilo) fragment-load in k_gemm is a CONTIGUOUS 1KB wave read.
__global__ __launch_bounds__(256) void k_prep(const float* __restrict__ W,
                                              unsigned short* __restrict__ wpk) {
    __shared__ float Wl[32][128];
    const int t = threadIdx.x, s = blockIdx.x;   // s in [0,8)
    // stage rows [s*32, s*32+32) of W (16 KB), coalesced
#pragma unroll
    for (int j = 0; j < 4; ++j) {
        int idx4 = t + j * 256;                  // 0..1023 float4s
        int kk = idx4 >> 5, c4 = (idx4 & 31) * 4;
        *(float4*)(&Wl[kk][c4]) = *(const float4*)(W + (size_t)(s * 32 + kk) * HC + c4);
    }
    __syncthreads();
#pragma unroll
    for (int j = 0; j < 4; ++j) {
        int o = t + j * 256;                     // 0..1023 output uint4s of this s
        int lane = o & 63, hilo = (o >> 6) & 1, ct = o >> 7;
        const int kk0 = (lane >> 4) * 8;
        const int col = ct * 16 + (lane & 15);
        unsigned short tmp[8];
#pragma unroll
        for (int e = 0; e < 8; ++e) {
            float f = Wl[kk0 + e][col];
            unsigned int u = __float_as_uint(f);
            if (hilo == 0) {
                tmp[e] = (unsigned short)(u >> 16);
            } else {
                float fl = f - __uint_as_float(u & 0xFFFF0000u);
                tmp[e] = (unsigned short)(__float_as_uint(fl) >> 16);
            }
        }
        uint4 ov;
        ov.x = tmp[0] | ((unsigned int)tmp[1] << 16);
        ov.y = tmp[2] | ((unsigned int)tmp[3] << 16);
        ov.z = tmp[4] | ((unsigned int)tmp[5] << 16);
        ov.w = tmp[6] | ((unsigned int)tmp[7] << 16);
        ((uint4*)wpk)[s * 1024 + o] = ov;
    }
}

// f32x8 -> bf16 hi/lo frags (truncation split)
__device__ inline void cvt_hilo(const float4& a, const float4& b, bf16x8& hi, bf16x8& lo) {
    const float f[8] = {a.x, a.y, a.z, a.w, b.x, b.y, b.z, b.w};
#pragma unroll
    for (int e = 0; e < 8; ++e) {
        unsigned int u = __float_as_uint(f[e]);
        hi[e] = (short)(u >> 16);
        float fl = f[e] - __uint_as_float(u & 0xFFFF0000u);
        lo[e] = (short)(__float_as_uint(fl) >> 16);
    }
}

// ---------- K_gemm v9: MFMA bf16x2 split GEMM, coalesced packed-B ----------
// One wave per 16 rows x 128 cols -> 2500 waves. Same half-kc register pipeline as v8
// (fixed-role buffers, static indices), but every B load is now a contiguous 1KB wave
// read from wpk (pre-swizzled to lane order) -> no 16-line micro-uncoalescing penalty,
// streams sequential 16KB chunks (L1/L2 friendly across co-resident waves).
__global__ __launch_bounds__(256) void k_gemm(const float* __restrict__ x,
                                              const unsigned short* __restrict__ wpk,
                                              const float* __restrict__ att_src,
                                              const float* __restrict__ att_dst,
                                              float* __restrict__ xp,
                                              float* __restrict__ asrc,
                                              float* __restrict__ adst,
                                              int* __restrict__ cnt, int n) {
    const int wave = blockIdx.x * 4 + (threadIdx.x >> 6);
    const int m0 = wave * 16;
    if (m0 >= n) return;
    const int l  = threadIdx.x & 63;
    const int lr = l & 15;
    const int q  = l >> 4;
    const int kq = q * 8;   // lane k-offset within a 32-k step

    f32x4 acc[8];
    const f32x4 zero = {0.f, 0.f, 0.f, 0.f};
#pragma unroll
    for (int j = 0; j < 8; ++j) acc[j] = zero;

    const int arow_idx = (m0 + lr < n) ? (m0 + lr) : (n - 1);
    const float* arow = x + (size_t)arow_idx * IN_CH + kq;
    const uint4* wb = (const uint4*)wpk + l;   // lane base; fragment (s,ct,h) at +((s*8+ct)*2+h)*64

    // A double buffer (ping-pong by s&1, static after full unroll)
    float4 aLb[2], aHb[2];
    aLb[0] = *(const float4*)(arow);
    aHb[0] = *(const float4*)(arow + 4);

    // B stage: fixed roles. sb*[0][j] = ct j (G0), sb*[1][j] = ct j+4 (G1).
    uint4 sbh[2][4], sbl[2][4];
#pragma unroll
    for (int j = 0; j < 4; ++j) {
        sbh[0][j] = wb[(j * 2 + 0) * 64];
        sbl[0][j] = wb[(j * 2 + 1) * 64];
    }

#pragma unroll
    for (int s = 0; s < 8; ++s) {
        const int kc = s * 32;
        const int p = s & 1, pn = p ^ 1;
        // ---- phase 0: issue G1(s) loads first; then cvt A; MFMA G0(s) ----
#pragma unroll
        for (int j = 0; j < 4; ++j) {
            sbh[1][j] = wb[((s * 8 + j + 4) * 2 + 0) * 64];
            sbl[1][j] = wb[((s * 8 + j + 4) * 2 + 1) * 64];
        }
        bf16x8 ahi, alo;
        cvt_hilo(aLb[p], aHb[p], ahi, alo);
#pragma unroll
        for (int j = 0; j < 4; ++j) {
            bf16x8 bhi = __builtin_bit_cast(bf16x8, sbh[0][j]);
            bf16x8 blo = __builtin_bit_cast(bf16x8, sbl[0][j]);
            acc[j] = __builtin_amdgcn_mfma_f32_16x16x32_bf16(alo, bhi, acc[j], 0, 0, 0);
            acc[j] = __builtin_amdgcn_mfma_f32_16x16x32_bf16(ahi, blo, acc[j], 0, 0, 0);
            acc[j] = __builtin_amdgcn_mfma_f32_16x16x32_bf16(ahi, bhi, acc[j], 0, 0, 0);
        }
        // ---- phase 1: issue G0(s+1) + A prefetch; MFMA G1(s) ----
        if (s < 7) {
#pragma unroll
            for (int j = 0; j < 4; ++j) {
                sbh[0][j] = wb[(((s + 1) * 8 + j) * 2 + 0) * 64];
                sbl[0][j] = wb[(((s + 1) * 8 + j) * 2 + 1) * 64];
            }
            aLb[pn] = *(const float4*)(arow + kc + 32);
            aHb[pn] = *(const float4*)(arow + kc + 36);
        }
#pragma unroll
        for (int j = 0; j < 4; ++j) {
            bf16x8 bhi = __builtin_bit_cast(bf16x8, sbh[1][j]);
            bf16x8 blo = __builtin_bit_cast(bf16x8, sbl[1][j]);
            acc[4 + j] = __builtin_amdgcn_mfma_f32_16x16x32_bf16(alo, bhi, acc[4 + j], 0, 0, 0);
            acc[4 + j] = __builtin_amdgcn_mfma_f32_16x16x32_bf16(ahi, blo, acc[4 + j], 0, 0, 0);
            acc[4 + j] = __builtin_amdgcn_mfma_f32_16x16x32_bf16(ahi, bhi, acc[4 + j], 0, 0, 0);
        }
    }

    // ---- fused attention dots: per row, per head, reduce over the 16 col-lanes ----
    float as_c[8], ad_c[8];
#pragma unroll
    for (int ct = 0; ct < 8; ++ct) {
        as_c[ct] = att_src[ct * 16 + lr];
        ad_c[ct] = att_dst[ct * 16 + lr];
    }
#pragma unroll
    for (int h = 0; h < 4; ++h)
#pragma unroll
        for (int r = 0; r < 4; ++r) {
            float s = acc[2 * h][r] * as_c[2 * h] + acc[2 * h + 1][r] * as_c[2 * h + 1];
            float d = acc[2 * h][r] * ad_c[2 * h] + acc[2 * h + 1][r] * ad_c[2 * h + 1];
            s += __shfl_xor(s, 1, 64); s += __shfl_xor(s, 2, 64);
            s += __shfl_xor(s, 4, 64); s += __shfl_xor(s, 8, 64);
            d += __shfl_xor(d, 1, 64); d += __shfl_xor(d, 2, 64);
            d += __shfl_xor(d, 4, 64); d += __shfl_xor(d, 8, 64);
            if (lr == h) {
                int row = m0 + q * 4 + r;
                if (row < n) {
                    asrc[(size_t)row * 4 + h] = s;
                    adst[(size_t)row * 4 + h] = d;
                }
            }
        }

    // ---- xp store (verified C/D layout) + cnt=1 self-loop ----
#pragma unroll
    for (int r = 0; r < 4; ++r) {
        int row = m0 + q * 4 + r;
        if (row < n) {
            if (lr == 8) cnt[row] = 1;
            float* xr = xp + (size_t)row * HC + lr;
#pragma unroll
            for (int ct = 0; ct < 8; ++ct)
                xr[ct * 16] = acc[ct][r];
        }
    }
}

// ---------- K_count ----------
__global__ void k_count(const int* __restrict__ ei, int* __restrict__ cnt, int E) {
    int e = blockIdx.x * blockDim.x + threadIdx.x;
    if (e >= E) return;
    atomicAdd(cnt + ei[E + e], 1);
}

// ---------- hierarchical scan: chunk=1024 ----------
__global__ __launch_bounds__(256) void k_scan1(const int* __restrict__ cnt,
                                               int* __restrict__ bsum, int n) {
    __shared__ int sm[256];
    int b = blockIdx.x, t = threadIdx.x;
    int base = b << 10;
    int s = 0;
#pragma unroll
    for (int j = 0; j < 4; ++j) {
        int i = base + t + j * 256;
        if (i < n) s += cnt[i];
    }
    sm[t] = s;
    __syncthreads();
    for (int d = 128; d > 0; d >>= 1) {
        if (t < d) sm[t] += sm[t + d];
        __syncthreads();
    }
    if (t == 0) bsum[b] = sm[0];
}

__global__ __launch_bounds__(1024) void k_scan2(int* __restrict__ bsum,
                                                int* __restrict__ offs,
                                                int nb, int n, int total) {
    __shared__ int sm[1024];
    int t = threadIdx.x;
    int orig = (t < nb) ? bsum[t] : 0;
    sm[t] = orig;
    __syncthreads();
    for (int d = 1; d < 1024; d <<= 1) {
        int v = (t >= d) ? sm[t - d] : 0;
        __syncthreads();
        sm[t] += v;
        __syncthreads();
    }
    if (t < nb) bsum[t] = sm[t] - orig;
    if (t == 0) offs[n] = total;
}

__global__ __launch_bounds__(256) void k_scan3(const int* __restrict__ cnt,
                                               const int* __restrict__ bsum,
                                               int* __restrict__ offs,
                                               int* __restrict__ cursor, int n) {
    __shared__ int sm[256];
    int b = blockIdx.x, t = threadIdx.x;
    int base = (b << 10) + t * 4;
    int c[4];
    int s = 0;
#pragma unroll
    for (int j = 0; j < 4; ++j) {
        int i = base + j;
        c[j] = (i < n) ? cnt[i] : 0;
        s += c[j];
    }
    sm[t] = s;
    __syncthreads();
    for (int d = 1; d < 256; d <<= 1) {
        int v = (t >= d) ? sm[t - d] : 0;
        __syncthreads();
        sm[t] += v;
        __syncthreads();
    }
    int excl = bsum[b] + ((t == 0) ? 0 : sm[t - 1]);
#pragma unroll
    for (int j = 0; j < 4; ++j) {
        int i = base + j;
        if (i < n) { offs[i] = excl; cursor[i] = excl; }
        excl += c[j];
    }
}

// ---------- K_fill ----------
__global__ void k_fill(const int* __restrict__ ei, int* __restrict__ cursor,
                       int* __restrict__ srcs, int E, int n) {
    int e = blockIdx.x * blockDim.x + threadIdx.x;
    if (e >= E + n) return;
    int s, d;
    if (e < E) { s = ei[e]; d = ei[E + e]; } else { s = d = e - E; }
    int pos = atomicAdd(cursor + d, 1);
    srcs[pos] = s;
}

// ---------- K_gat: one wave per dst node (unchanged) ----------
__global__ __launch_bounds__(256) void k_gat(const int* __restrict__ offs,
                                             const int* __restrict__ srcs,
                                             const float* __restrict__ asrc,
                                             const float* __restrict__ adst,
                                             const float* __restrict__ xp,
                                             const float* __restrict__ bias,
                                             float* __restrict__ out, int n) {
    __shared__ int sS[4][128];
    const int wid = threadIdx.x >> 6;
    const int wave = blockIdx.x * 4 + wid;
    if (wave >= n) return;
    const int lane = threadIdx.x & 63;
    const int d = wave;
    const int start = offs[d], end = offs[d + 1];
    const int deg = end - start;

    const int h = lane & 3;
    const float ad_h = adst[(size_t)d * 4 + h];
    float m = -1e30f, Z = 0.f;

    for (int c0 = start; c0 < end; c0 += 128) {
        const int cn = min(128, end - c0);
        if (c0 + lane < end)      sS[wid][lane]      = srcs[c0 + lane];
        if (c0 + 64 + lane < end) sS[wid][64 + lane] = srcs[c0 + 64 + lane];
        asm volatile("s_waitcnt lgkmcnt(0)" ::: "memory");
        for (int i = (lane >> 2); i < cn; i += 16) {
            int s = sS[wid][i];
            float t = asrc[(size_t)s * 4 + h] + ad_h;
            t = t > 0.f ? t : NEG_SLOPE * t;
            float nm = fmaxf(m, t);
            Z = Z * __expf(m - nm) + __expf(t - nm);
            m = nm;
        }
    }
#pragma unroll
    for (int off = 4; off < 64; off <<= 1) {
        float om = __shfl_xor(m, off, 64);
        float oZ = __shfl_xor(Z, off, 64);
        float nm = fmaxf(m, om);
        Z = Z * __expf(m - nm) + oZ * __expf(om - nm);
        m = nm;
    }

    const int cl = lane & 15;
    const int eg = lane >> 4;
    const int hh = cl >> 2;
    const float m2  = __shfl(m, hh, 64);
    const float rZ  = 1.0f / __shfl(Z, hh, 64);
    const float ad2 = __shfl(ad_h, hh, 64);

    float4 a0 = make_float4(0.f, 0.f, 0.f, 0.f);
    float4 a1 = make_float4(0.f, 0.f, 0.f, 0.f);

    for (int c0 = start; c0 < end; c0 += 128) {
        const int cn = min(128, end - c0);
        if (deg > 128) {
            if (c0 + lane < end)      sS[wid][lane]      = srcs[c0 + lane];
            if (c0 + 64 + lane < end) sS[wid][64 + lane] = srcs[c0 + 64 + lane];
            asm volatile("s_waitcnt lgkmcnt(0)" ::: "memory");
        }
        const int full = cn & ~7;
        int i = 0;
        for (; i < full; i += 8) {
            int sa = sS[wid][i + eg];
            int sb = sS[wid][i + 4 + eg];
            float ta = asrc[(size_t)sa * 4 + hh] + ad2;
            float tb = asrc[(size_t)sb * 4 + hh] + ad2;
            const float4* xa = (const float4*)(xp + (size_t)sa * HC + cl * 8);
            const float4* xb = (const float4*)(xp + (size_t)sb * HC + cl * 8);
            float4 va0 = xa[0], va1 = xa[1];
            float4 vb0 = xb[0], vb1 = xb[1];
            ta = ta > 0.f ? ta : NEG_SLOPE * ta;
            tb = tb > 0.f ? tb : NEG_SLOPE * tb;
            float aa = __expf(ta - m2) * rZ;
            float ab = __expf(tb - m2) * rZ;
            a0.x += aa * va0.x; a0.y += aa * va0.y; a0.z += aa * va0.z; a0.w += aa * va0.w;
            a1.x += aa * va1.x; a1.y += aa * va1.y; a1.z += aa * va1.z; a1.w += aa * va1.w;
            a0.x += ab * vb0.x; a0.y += ab * vb0.y; a0.z += ab * vb0.z; a0.w += ab * vb0.w;
            a1.x += ab * vb1.x; a1.y += ab * vb1.y; a1.z += ab * vb1.z; a1.w += ab * vb1.w;
        }
        for (; i < cn; i += 4) {
            if (i + eg < cn) {
                int s = sS[wid][i + eg];
                float t = asrc[(size_t)s * 4 + hh] + ad2;
                const float4* xr = (const float4*)(xp + (size_t)s * HC + cl * 8);
                float4 v0 = xr[0], v1 = xr[1];
                t = t > 0.f ? t : NEG_SLOPE * t;
                float al = __expf(t - m2) * rZ;
                a0.x += al * v0.x; a0.y += al * v0.y; a0.z += al * v0.z; a0.w += al * v0.w;
                a1.x += al * v1.x; a1.y += al * v1.y; a1.z += al * v1.z; a1.w += al * v1.w;
            }
        }
    }

#pragma unroll
    for (int off = 16; off < 64; off <<= 1) {
        a0.x += __shfl_xor(a0.x, off, 64); a0.y += __shfl_xor(a0.y, off, 64);
        a0.z += __shfl_xor(a0.z, off, 64); a0.w += __shfl_xor(a0.w, off, 64);
        a1.x += __shfl_xor(a1.x, off, 64); a1.y += __shfl_xor(a1.y, off, 64);
        a1.z += __shfl_xor(a1.z, off, 64); a1.w += __shfl_xor(a1.w, off, 64);
    }

    if (eg == 0) {
        const float4* bp = (const float4*)bias + cl * 2;
        float4 b0 = bp[0], b1 = bp[1];
        float4 o0, o1;
        o0.x = fmaxf(a0.x + b0.x, 0.f); o0.y = fmaxf(a0.y + b0.y, 0.f);
        o0.z = fmaxf(a0.z + b0.z, 0.f); o0.w = fmaxf(a0.w + b0.w, 0.f);
        o1.x = fmaxf(a1.x + b1.x, 0.f); o1.y = fmaxf(a1.y + b1.y, 0.f);
        o1.z = fmaxf(a1.z + b1.z, 0.f); o1.w = fmaxf(a1.w + b1.w, 0.f);
        float4* op = (float4*)(out + (size_t)d * HC) + cl * 2;
        op[0] = o0; op[1] = o1;
    }
}

extern "C" void kernel_launch(void* const* d_in, const int* in_sizes, int n_in,
                              void* d_out, int out_size, void* d_ws, size_t ws_size,
                              hipStream_t stream) {
    const float* x       = (const float*)d_in[0];
    const int*   ei      = (const int*)d_in[1];
    const float* W       = (const float*)d_in[3];
    const float* att_src = (const float*)d_in[4];
    const float* att_dst = (const float*)d_in[5];
    const float* bias    = (const float*)d_in[6];
    float* out = (float*)d_out;

    const int n = in_sizes[0] / IN_CH;   // 40000
    const int E = in_sizes[1] / 2;       // 640000
    const int EN = E + n;
    const int NB = (n + 1023) >> 10;     // scan chunks

    // workspace layout
    float* xp   = (float*)d_ws;                          // n*128 f32
    float* asrc = xp + (size_t)n * HC;                   // n*4
    float* adst = asrc + (size_t)n * HEADS;              // n*4
    int*   cnt    = (int*)(adst + (size_t)n * HEADS);    // n
    int*   offs   = cnt + n;                             // n+1
    int*   cursor = offs + n + 1;                        // n
    int*   bsum   = cursor + n;                          // NB
    int*   srcs   = bsum + 1024;                         // E+n
    unsigned short* wpk = (unsigned short*)(((uintptr_t)(srcs + EN) + 63) & ~(uintptr_t)63);  // 128 KB

    k_prep<<<8, 256, 0, stream>>>(W, wpk);
    {
        const int nwaves = (n + 15) / 16;
        k_gemm<<<(nwaves + 3) / 4, 256, 0, stream>>>(x, wpk, att_src, att_dst,
                                                     xp, asrc, adst, cnt, n);
    }
    k_count<<<(E + 255) / 256, 256, 0, stream>>>(ei, cnt, E);
    k_scan1<<<NB, 256, 0, stream>>>(cnt, bsum, n);
    k_scan2<<<1, 1024, 0, stream>>>(bsum, offs, NB, n, EN);
    k_scan3<<<NB, 256, 0, stream>>>(cnt, bsum, offs, cursor, n);
    k_fill<<<(EN + 255) / 256, 256, 0, stream>>>(ei, cursor, srcs, E, n);
    k_gat<<<(n + 3) / 4, 256, 0, stream>>>(offs, srcs, asrc, adst, xp, bias, out, n);
}

// Round 10
// 140.819 us; speedup vs baseline: 1.3143x; 1.1253x over previous
//
#include <hip/hip_runtime.h>
#include <hip/hip_bf16.h>
#include <stdint.h>

#define IN_CH 256
#define HC    128   // HEADS * C
#define HEADS 4
#define CPH   32    // channels per head
#define NEG_SLOPE 0.2f

using f32x4  = __attribute__((ext_vector_type(4))) float;
using bf16x8 = __attribute__((ext_vector_type(8))) short;
using f16x8  = __attribute__((ext_vector_type(8))) _Float16;

// ---------- K_prep: W [256][128] f32 -> wpk, lane-order packed bf16 hi/lo ----------
// wpk layout: uint4 index ((s*8 + ct)*2 + hilo)*64 + lane, s=k-step(32), ct=col-tile(16).
// Lane l's fragment: col = ct*16 + (l&15), k = s*32 + (l>>4)*8 + e  (e=0..7).
// Each (s,ct,hilo) fragment-load in k_gemm is a CONTIGUOUS 1KB wave read.
__global__ __launch_bounds__(256) void k_prep(const float* __restrict__ W,
                                              unsigned short* __restrict__ wpk) {
    __shared__ float Wl[32][128];
    const int t = threadIdx.x, s = blockIdx.x;   // s in [0,8)
#pragma unroll
    for (int j = 0; j < 4; ++j) {
        int idx4 = t + j * 256;                  // 0..1023 float4s
        int kk = idx4 >> 5, c4 = (idx4 & 31) * 4;
        *(float4*)(&Wl[kk][c4]) = *(const float4*)(W + (size_t)(s * 32 + kk) * HC + c4);
    }
    __syncthreads();
#pragma unroll
    for (int j = 0; j < 4; ++j) {
        int o = t + j * 256;                     // 0..1023 output uint4s of this s
        int lane = o & 63, hilo = (o >> 6) & 1, ct = o >> 7;
        const int kk0 = (lane >> 4) * 8;
        const int col = ct * 16 + (lane & 15);
        unsigned short tmp[8];
#pragma unroll
        for (int e = 0; e < 8; ++e) {
            float f = Wl[kk0 + e][col];
            unsigned int u = __float_as_uint(f);
            if (hilo == 0) {
                tmp[e] = (unsigned short)(u >> 16);
            } else {
                float fl = f - __uint_as_float(u & 0xFFFF0000u);
                tmp[e] = (unsigned short)(__float_as_uint(fl) >> 16);
            }
        }
        uint4 ov;
        ov.x = tmp[0] | ((unsigned int)tmp[1] << 16);
        ov.y = tmp[2] | ((unsigned int)tmp[3] << 16);
        ov.z = tmp[4] | ((unsigned int)tmp[5] << 16);
        ov.w = tmp[6] | ((unsigned int)tmp[7] << 16);
        ((uint4*)wpk)[s * 1024 + o] = ov;
    }
}

// f32x8 -> bf16 hi/lo frags (truncation split)
__device__ inline void cvt_hilo(const float4& a, const float4& b, bf16x8& hi, bf16x8& lo) {
    const float f[8] = {a.x, a.y, a.z, a.w, b.x, b.y, b.z, b.w};
#pragma unroll
    for (int e = 0; e < 8; ++e) {
        unsigned int u = __float_as_uint(f[e]);
        hi[e] = (short)(u >> 16);
        float fl = f[e] - __uint_as_float(u & 0xFFFF0000u);
        lo[e] = (short)(__float_as_uint(fl) >> 16);
    }
}

// ---------- K_gemm v10: MFMA bf16x2 split GEMM, coalesced packed-B, fp16 xp out ----
// One wave per 16 rows x 128 cols -> 2500 waves. Half-kc register pipeline with
// fixed-role buffers; every B load is a contiguous 1KB wave read from wpk.
// xp now stored as fp16 (RN cvt): halves k_gat's gather traffic; attention dots
// still computed from the f32 accumulators (full precision).
__global__ __launch_bounds__(256) void k_gemm(const float* __restrict__ x,
                                              const unsigned short* __restrict__ wpk,
                                              const float* __restrict__ att_src,
                                              const float* __restrict__ att_dst,
                                              unsigned short* __restrict__ xp,
                                              float* __restrict__ asrc,
                                              float* __restrict__ adst,
                                              int* __restrict__ cnt, int n) {
    const int wave = blockIdx.x * 4 + (threadIdx.x >> 6);
    const int m0 = wave * 16;
    if (m0 >= n) return;
    const int l  = threadIdx.x & 63;
    const int lr = l & 15;
    const int q  = l >> 4;
    const int kq = q * 8;   // lane k-offset within a 32-k step

    f32x4 acc[8];
    const f32x4 zero = {0.f, 0.f, 0.f, 0.f};
#pragma unroll
    for (int j = 0; j < 8; ++j) acc[j] = zero;

    const int arow_idx = (m0 + lr < n) ? (m0 + lr) : (n - 1);
    const float* arow = x + (size_t)arow_idx * IN_CH + kq;
    const uint4* wb = (const uint4*)wpk + l;   // lane base

    float4 aLb[2], aHb[2];
    aLb[0] = *(const float4*)(arow);
    aHb[0] = *(const float4*)(arow + 4);

    uint4 sbh[2][4], sbl[2][4];
#pragma unroll
    for (int j = 0; j < 4; ++j) {
        sbh[0][j] = wb[(j * 2 + 0) * 64];
        sbl[0][j] = wb[(j * 2 + 1) * 64];
    }

#pragma unroll
    for (int s = 0; s < 8; ++s) {
        const int kc = s * 32;
        const int p = s & 1, pn = p ^ 1;
        // phase 0: issue G1(s) loads; cvt A; MFMA G0(s)
#pragma unroll
        for (int j = 0; j < 4; ++j) {
            sbh[1][j] = wb[((s * 8 + j + 4) * 2 + 0) * 64];
            sbl[1][j] = wb[((s * 8 + j + 4) * 2 + 1) * 64];
        }
        bf16x8 ahi, alo;
        cvt_hilo(aLb[p], aHb[p], ahi, alo);
#pragma unroll
        for (int j = 0; j < 4; ++j) {
            bf16x8 bhi = __builtin_bit_cast(bf16x8, sbh[0][j]);
            bf16x8 blo = __builtin_bit_cast(bf16x8, sbl[0][j]);
            acc[j] = __builtin_amdgcn_mfma_f32_16x16x32_bf16(alo, bhi, acc[j], 0, 0, 0);
            acc[j] = __builtin_amdgcn_mfma_f32_16x16x32_bf16(ahi, blo, acc[j], 0, 0, 0);
            acc[j] = __builtin_amdgcn_mfma_f32_16x16x32_bf16(ahi, bhi, acc[j], 0, 0, 0);
        }
        // phase 1: issue G0(s+1) + A prefetch; MFMA G1(s)
        if (s < 7) {
#pragma unroll
            for (int j = 0; j < 4; ++j) {
                sbh[0][j] = wb[(((s + 1) * 8 + j) * 2 + 0) * 64];
                sbl[0][j] = wb[(((s + 1) * 8 + j) * 2 + 1) * 64];
            }
            aLb[pn] = *(const float4*)(arow + kc + 32);
            aHb[pn] = *(const float4*)(arow + kc + 36);
        }
#pragma unroll
        for (int j = 0; j < 4; ++j) {
            bf16x8 bhi = __builtin_bit_cast(bf16x8, sbh[1][j]);
            bf16x8 blo = __builtin_bit_cast(bf16x8, sbl[1][j]);
            acc[4 + j] = __builtin_amdgcn_mfma_f32_16x16x32_bf16(alo, bhi, acc[4 + j], 0, 0, 0);
            acc[4 + j] = __builtin_amdgcn_mfma_f32_16x16x32_bf16(ahi, blo, acc[4 + j], 0, 0, 0);
            acc[4 + j] = __builtin_amdgcn_mfma_f32_16x16x32_bf16(ahi, bhi, acc[4 + j], 0, 0, 0);
        }
    }

    // ---- fused attention dots (f32 accumulators, full precision) ----
    float as_c[8], ad_c[8];
#pragma unroll
    for (int ct = 0; ct < 8; ++ct) {
        as_c[ct] = att_src[ct * 16 + lr];
        ad_c[ct] = att_dst[ct * 16 + lr];
    }
#pragma unroll
    for (int h = 0; h < 4; ++h)
#pragma unroll
        for (int r = 0; r < 4; ++r) {
            float s = acc[2 * h][r] * as_c[2 * h] + acc[2 * h + 1][r] * as_c[2 * h + 1];
            float d = acc[2 * h][r] * ad_c[2 * h] + acc[2 * h + 1][r] * ad_c[2 * h + 1];
            s += __shfl_xor(s, 1, 64); s += __shfl_xor(s, 2, 64);
            s += __shfl_xor(s, 4, 64); s += __shfl_xor(s, 8, 64);
            d += __shfl_xor(d, 1, 64); d += __shfl_xor(d, 2, 64);
            d += __shfl_xor(d, 4, 64); d += __shfl_xor(d, 8, 64);
            if (lr == h) {
                int row = m0 + q * 4 + r;
                if (row < n) {
                    asrc[(size_t)row * 4 + h] = s;
                    adst[(size_t)row * 4 + h] = d;
                }
            }
        }

    // ---- xp store as fp16 (RN) + cnt=1 self-loop ----
#pragma unroll
    for (int r = 0; r < 4; ++r) {
        int row = m0 + q * 4 + r;
        if (row < n) {
            if (lr == 8) cnt[row] = 1;
            unsigned short* xr = xp + (size_t)row * HC + lr;
#pragma unroll
            for (int ct = 0; ct < 8; ++ct) {
                _Float16 hv = (_Float16)acc[ct][r];
                xr[ct * 16] = __builtin_bit_cast(unsigned short, hv);
            }
        }
    }
}

// ---------- K_count ----------
__global__ void k_count(const int* __restrict__ ei, int* __restrict__ cnt, int E) {
    int e = blockIdx.x * blockDim.x + threadIdx.x;
    if (e >= E) return;
    atomicAdd(cnt + ei[E + e], 1);
}

// ---------- hierarchical scan: chunk=1024 ----------
__global__ __launch_bounds__(256) void k_scan1(const int* __restrict__ cnt,
                                               int* __restrict__ bsum, int n) {
    __shared__ int sm[256];
    int b = blockIdx.x, t = threadIdx.x;
    int base = b << 10;
    int s = 0;
#pragma unroll
    for (int j = 0; j < 4; ++j) {
        int i = base + t + j * 256;
        if (i < n) s += cnt[i];
    }
    sm[t] = s;
    __syncthreads();
    for (int d = 128; d > 0; d >>= 1) {
        if (t < d) sm[t] += sm[t + d];
        __syncthreads();
    }
    if (t == 0) bsum[b] = sm[0];
}

__global__ __launch_bounds__(1024) void k_scan2(int* __restrict__ bsum,
                                                int* __restrict__ offs,
                                                int nb, int n, int total) {
    __shared__ int sm[1024];
    int t = threadIdx.x;
    int orig = (t < nb) ? bsum[t] : 0;
    sm[t] = orig;
    __syncthreads();
    for (int d = 1; d < 1024; d <<= 1) {
        int v = (t >= d) ? sm[t - d] : 0;
        __syncthreads();
        sm[t] += v;
        __syncthreads();
    }
    if (t < nb) bsum[t] = sm[t] - orig;
    if (t == 0) offs[n] = total;
}

__global__ __launch_bounds__(256) void k_scan3(const int* __restrict__ cnt,
                                               const int* __restrict__ bsum,
                                               int* __restrict__ offs,
                                               int* __restrict__ cursor, int n) {
    __shared__ int sm[256];
    int b = blockIdx.x, t = threadIdx.x;
    int base = (b << 10) + t * 4;
    int c[4];
    int s = 0;
#pragma unroll
    for (int j = 0; j < 4; ++j) {
        int i = base + j;
        c[j] = (i < n) ? cnt[i] : 0;
        s += c[j];
    }
    sm[t] = s;
    __syncthreads();
    for (int d = 1; d < 256; d <<= 1) {
        int v = (t >= d) ? sm[t - d] : 0;
        __syncthreads();
        sm[t] += v;
        __syncthreads();
    }
    int excl = bsum[b] + ((t == 0) ? 0 : sm[t - 1]);
#pragma unroll
    for (int j = 0; j < 4; ++j) {
        int i = base + j;
        if (i < n) { offs[i] = excl; cursor[i] = excl; }
        excl += c[j];
    }
}

// ---------- K_fill ----------
__global__ void k_fill(const int* __restrict__ ei, int* __restrict__ cursor,
                       int* __restrict__ srcs, int E, int n) {
    int e = blockIdx.x * blockDim.x + threadIdx.x;
    if (e >= E + n) return;
    int s, d;
    if (e < E) { s = ei[e]; d = ei[E + e]; } else { s = d = e - E; }
    int pos = atomicAdd(cursor + d, 1);
    srcs[pos] = s;
}

// ---------- K_gat v3: one wave per dst node; fp16 xp gather (half traffic) ----------
__global__ __launch_bounds__(256) void k_gat(const int* __restrict__ offs,
                                             const int* __restrict__ srcs,
                                             const float* __restrict__ asrc,
                                             const float* __restrict__ adst,
                                             const unsigned short* __restrict__ xp,
                                             const float* __restrict__ bias,
                                             float* __restrict__ out, int n) {
    __shared__ int sS[4][128];
    const int wid = threadIdx.x >> 6;
    const int wave = blockIdx.x * 4 + wid;
    if (wave >= n) return;
    const int lane = threadIdx.x & 63;
    const int d = wave;
    const int start = offs[d], end = offs[d + 1];
    const int deg = end - start;

    const int h = lane & 3;
    const float ad_h = adst[(size_t)d * 4 + h];
    float m = -1e30f, Z = 0.f;

    // ---- pass 1: online softmax stats over chunks of <=128 edges ----
    for (int c0 = start; c0 < end; c0 += 128) {
        const int cn = min(128, end - c0);
        if (c0 + lane < end)      sS[wid][lane]      = srcs[c0 + lane];
        if (c0 + 64 + lane < end) sS[wid][64 + lane] = srcs[c0 + 64 + lane];
        asm volatile("s_waitcnt lgkmcnt(0)" ::: "memory");
        for (int i = (lane >> 2); i < cn; i += 16) {
            int s = sS[wid][i];
            float t = asrc[(size_t)s * 4 + h] + ad_h;
            t = t > 0.f ? t : NEG_SLOPE * t;
            float nm = fmaxf(m, t);
            Z = Z * __expf(m - nm) + __expf(t - nm);
            m = nm;
        }
    }
#pragma unroll
    for (int off = 4; off < 64; off <<= 1) {
        float om = __shfl_xor(m, off, 64);
        float oZ = __shfl_xor(Z, off, 64);
        float nm = fmaxf(m, om);
        Z = Z * __expf(m - nm) + oZ * __expf(om - nm);
        m = nm;
    }

    // ---- pass 2: fp16 rows, 16B/lane, 8 edges in flight ----
    const int cl = lane & 15;   // channel lane: channels [cl*8, cl*8+8)
    const int eg = lane >> 4;   // edge slot (4 edges in parallel)
    const int hh = cl >> 2;     // head owning this channel slice
    const float m2  = __shfl(m, hh, 64);
    const float rZ  = 1.0f / __shfl(Z, hh, 64);
    const float ad2 = __shfl(ad_h, hh, 64);

    float4 a0 = make_float4(0.f, 0.f, 0.f, 0.f);
    float4 a1 = make_float4(0.f, 0.f, 0.f, 0.f);

    for (int c0 = start; c0 < end; c0 += 128) {
        const int cn = min(128, end - c0);
        if (deg > 128) {
            if (c0 + lane < end)      sS[wid][lane]      = srcs[c0 + lane];
            if (c0 + 64 + lane < end) sS[wid][64 + lane] = srcs[c0 + 64 + lane];
            asm volatile("s_waitcnt lgkmcnt(0)" ::: "memory");
        }
        const int full = cn & ~7;
        int i = 0;
        for (; i < full; i += 8) {  // 8 edges in flight
            int sa = sS[wid][i + eg];
            int sb = sS[wid][i + 4 + eg];
            float ta = asrc[(size_t)sa * 4 + hh] + ad2;
            float tb = asrc[(size_t)sb * 4 + hh] + ad2;
            uint4 ua = *(const uint4*)(xp + (size_t)sa * HC + cl * 8);
            uint4 ub = *(const uint4*)(xp + (size_t)sb * HC + cl * 8);
            f16x8 va = __builtin_bit_cast(f16x8, ua);
            f16x8 vb = __builtin_bit_cast(f16x8, ub);
            ta = ta > 0.f ? ta : NEG_SLOPE * ta;
            tb = tb > 0.f ? tb : NEG_SLOPE * tb;
            float aa = __expf(ta - m2) * rZ;
            float ab = __expf(tb - m2) * rZ;
            a0.x += aa * (float)va[0]; a0.y += aa * (float)va[1];
            a0.z += aa * (float)va[2]; a0.w += aa * (float)va[3];
            a1.x += aa * (float)va[4]; a1.y += aa * (float)va[5];
            a1.z += aa * (float)va[6]; a1.w += aa * (float)va[7];
            a0.x += ab * (float)vb[0]; a0.y += ab * (float)vb[1];
            a0.z += ab * (float)vb[2]; a0.w += ab * (float)vb[3];
            a1.x += ab * (float)vb[4]; a1.y += ab * (float)vb[5];
            a1.z += ab * (float)vb[6]; a1.w += ab * (float)vb[7];
        }
        for (; i < cn; i += 4) {  // tail: exec-masked
            if (i + eg < cn) {
                int s = sS[wid][i + eg];
                float t = asrc[(size_t)s * 4 + hh] + ad2;
                uint4 u = *(const uint4*)(xp + (size_t)s * HC + cl * 8);
                f16x8 v = __builtin_bit_cast(f16x8, u);
                t = t > 0.f ? t : NEG_SLOPE * t;
                float al = __expf(t - m2) * rZ;
                a0.x += al * (float)v[0]; a0.y += al * (float)v[1];
                a0.z += al * (float)v[2]; a0.w += al * (float)v[3];
                a1.x += al * (float)v[4]; a1.y += al * (float)v[5];
                a1.z += al * (float)v[6]; a1.w += al * (float)v[7];
            }
        }
    }

    // reduce across the 4 edge groups
#pragma unroll
    for (int off = 16; off < 64; off <<= 1) {
        a0.x += __shfl_xor(a0.x, off, 64); a0.y += __shfl_xor(a0.y, off, 64);
        a0.z += __shfl_xor(a0.z, off, 64); a0.w += __shfl_xor(a0.w, off, 64);
        a1.x += __shfl_xor(a1.x, off, 64); a1.y += __shfl_xor(a1.y, off, 64);
        a1.z += __shfl_xor(a1.z, off, 64); a1.w += __shfl_xor(a1.w, off, 64);
    }

    if (eg == 0) {
        const float4* bp = (const float4*)bias + cl * 2;
        float4 b0 = bp[0], b1 = bp[1];
        float4 o0, o1;
        o0.x = fmaxf(a0.x + b0.x, 0.f); o0.y = fmaxf(a0.y + b0.y, 0.f);
        o0.z = fmaxf(a0.z + b0.z, 0.f); o0.w = fmaxf(a0.w + b0.w, 0.f);
        o1.x = fmaxf(a1.x + b1.x, 0.f); o1.y = fmaxf(a1.y + b1.y, 0.f);
        o1.z = fmaxf(a1.z + b1.z, 0.f); o1.w = fmaxf(a1.w + b1.w, 0.f);
        float4* op = (float4*)(out + (size_t)d * HC) + cl * 2;
        op[0] = o0; op[1] = o1;
    }
}

extern "C" void kernel_launch(void* const* d_in, const int* in_sizes, int n_in,
                              void* d_out, int out_size, void* d_ws, size_t ws_size,
                              hipStream_t stream) {
    const float* x       = (const float*)d_in[0];
    const int*   ei      = (const int*)d_in[1];
    const float* W       = (const float*)d_in[3];
    const float* att_src = (const float*)d_in[4];
    const float* att_dst = (const float*)d_in[5];
    const float* bias    = (const float*)d_in[6];
    float* out = (float*)d_out;

    const int n = in_sizes[0] / IN_CH;   // 40000
    const int E = in_sizes[1] / 2;       // 640000
    const int EN = E + n;
    const int NB = (n + 1023) >> 10;     // scan chunks

    // workspace layout
    unsigned short* xp = (unsigned short*)d_ws;          // n*128 fp16
    float* asrc = (float*)(xp + (size_t)n * HC);         // n*4
    float* adst = asrc + (size_t)n * HEADS;              // n*4
    int*   cnt    = (int*)(adst + (size_t)n * HEADS);    // n
    int*   offs   = cnt + n;                             // n+1
    int*   cursor = offs + n + 1;                        // n
    int*   bsum   = cursor + n;                          // NB
    int*   srcs   = bsum + 1024;                         // E+n
    unsigned short* wpk = (unsigned short*)(((uintptr_t)(srcs + EN) + 63) & ~(uintptr_t)63);  // 128 KB

    k_prep<<<8, 256, 0, stream>>>(W, wpk);
    {
        const int nwaves = (n + 15) / 16;
        k_gemm<<<(nwaves + 3) / 4, 256, 0, stream>>>(x, wpk, att_src, att_dst,
                                                     xp, asrc, adst, cnt, n);
    }
    k_count<<<(E + 255) / 256, 256, 0, stream>>>(ei, cnt, E);
    k_scan1<<<NB, 256, 0, stream>>>(cnt, bsum, n);
    k_scan2<<<1, 1024, 0, stream>>>(bsum, offs, NB, n, EN);
    k_scan3<<<NB, 256, 0, stream>>>(cnt, bsum, offs, cursor, n);
    k_fill<<<(EN + 255) / 256, 256, 0, stream>>>(ei, cursor, srcs, E, n);
    k_gat<<<(n + 3) / 4, 256, 0, stream>>>(offs, srcs, asrc, adst, xp, bias, out, n);
}